// Round 7
// baseline (54.832 us; speedup 1.0000x reference)
//
#include <hip/hip_runtime.h>

#define D 64
#define STR 72    // LDS row stride in bf16 elems (kept identical to r4)
#define WAVES 4   // independent waves per block, one sequence each

typedef __attribute__((ext_vector_type(8))) short bf16x8;
typedef __attribute__((ext_vector_type(4))) float f32x4;
typedef __attribute__((ext_vector_type(4))) unsigned int u32x4;

static __device__ __forceinline__ unsigned short f2bf(float f) {
  unsigned u = __builtin_bit_cast(unsigned, f);
  u += 0x7fffu + ((u >> 16) & 1u);  // RNE
  return (unsigned short)(u >> 16);
}

// r4's exact wave-private LDS ordering macro (passing config)
#define LDSWAIT() asm volatile("s_waitcnt lgkmcnt(0)" ::: "memory")

// BISECTION KERNEL: r4 with exactly ONE delta — hf/vf fragments loaded
// directly from global (masked-to-zero; value-identical to r4's zero-padded
// LDS staging). LDS buffer, P addresses (tile-disjoint rows), softmax,
// PV structure, epilogue: all r4 verbatim.
__global__ __launch_bounds__(256, 4)
void seq_attn_kernel(const float* __restrict__ h,
                     const int* __restrict__ sse,  // int32 (JAX x64 disabled)
                     float* __restrict__ out) {
  __shared__ unsigned short HsAll[WAVES * 64 * STR];  // same 36.9 KB as r4 (control)

  const int tid = threadIdx.x;
  const int w = tid >> 6;
  const int lane = tid & 63;
  unsigned short* Hs = HsAll + w * (64 * STR);  // wave-private; holds P tiles only now

  const int s = blockIdx.x + gridDim.x * w;
  const int start = sse[2 * s];
  const int L = sse[2 * s + 1] - start;
  const int nt = (L + 15) >> 4;  // live 16-row tiles
  const int g = lane >> 4;
  const int c16 = lane & 15;

  const float* src = h + (size_t)start * D;

  // ---- hf: A-layout H fragments from global; rows >= L exact 0 (== r4 Hs) ----
  bf16x8 hf[4][2];
  {
    const float4 fz = make_float4(0.f, 0.f, 0.f, 0.f);
    #pragma unroll
    for (int t = 0; t < 4; ++t) {
      const int row = t * 16 + c16;
      const bool ok = (row < L);
      float4 r0a, r0b, r1a, r1b;
      const float* p0 = src + (size_t)row * D + g * 8;
      r0a = ok ? *(const float4*)p0 : fz;
      r0b = ok ? *(const float4*)(p0 + 4) : fz;
      r1a = ok ? *(const float4*)(p0 + 32) : fz;
      r1b = ok ? *(const float4*)(p0 + 36) : fz;
      u32x4 w0, w1;
      w0[0] = (unsigned)f2bf(r0a.x) | ((unsigned)f2bf(r0a.y) << 16);
      w0[1] = (unsigned)f2bf(r0a.z) | ((unsigned)f2bf(r0a.w) << 16);
      w0[2] = (unsigned)f2bf(r0b.x) | ((unsigned)f2bf(r0b.y) << 16);
      w0[3] = (unsigned)f2bf(r0b.z) | ((unsigned)f2bf(r0b.w) << 16);
      w1[0] = (unsigned)f2bf(r1a.x) | ((unsigned)f2bf(r1a.y) << 16);
      w1[1] = (unsigned)f2bf(r1a.z) | ((unsigned)f2bf(r1a.w) << 16);
      w1[2] = (unsigned)f2bf(r1b.x) | ((unsigned)f2bf(r1b.y) << 16);
      w1[3] = (unsigned)f2bf(r1b.z) | ((unsigned)f2bf(r1b.w) << 16);
      hf[t][0] = __builtin_bit_cast(bf16x8, w0);
      hf[t][1] = __builtin_bit_cast(bf16x8, w1);
    }
  }

  // ---- vf: H^T fragments from global scalar loads; keys >= L exact 0 (== r4) ----
  bf16x8 vf[4][2];
  #pragma unroll
  for (int t = 0; t < 4; ++t) {
    const int col = t * 16 + c16;
    #pragma unroll
    for (int kb = 0; kb < 2; ++kb) {
      u32x4 wv;
      #pragma unroll
      for (int dd = 0; dd < 4; ++dd) {
        const int k0 = kb * 32 + g * 8 + 2 * dd;
        const float f0 = (k0 < L) ? src[(size_t)k0 * D + col] : 0.f;
        const float f1 = (k0 + 1 < L) ? src[(size_t)(k0 + 1) * D + col] : 0.f;
        wv[dd] = (unsigned)f2bf(f0) | ((unsigned)f2bf(f1) << 16);
      }
      vf[t][kb] = __builtin_bit_cast(bf16x8, wv);
    }
  }

  // ---- per 16-row tile: QK^T -> softmax -> P restage -> PV -> store (r4 verbatim) ----
  #pragma unroll
  for (int ti = 0; ti < 4; ++ti) {
    if (ti >= nt) continue;  // wave-uniform

    f32x4 acc[4];
    #pragma unroll
    for (int tj = 0; tj < 4; ++tj) {
      f32x4 z = {0.f, 0.f, 0.f, 0.f};
      acc[tj] = z;
    }
    #pragma unroll
    for (int tj = 0; tj < 4; ++tj)
      #pragma unroll
      for (int kb = 0; kb < 2; ++kb)
        acc[tj] = __builtin_amdgcn_mfma_f32_16x16x32_bf16(
            hf[ti][kb], hf[tj][kb], acc[tj], 0, 0, 0);

    // softmax over key index. C layout: row = 16*ti + 4*g + r, col = 16*tj + c16.
    float inv[4];
    #pragma unroll
    for (int r = 0; r < 4; ++r) {
      float mx = -1e30f;
      #pragma unroll
      for (int tj = 0; tj < 4; ++tj) {
        const float sv = (tj * 16 + c16 < L) ? acc[tj][r] : -1e30f;
        acc[tj][r] = sv;
        mx = fmaxf(mx, sv);
      }
      #pragma unroll
      for (int off = 1; off < 16; off <<= 1)
        mx = fmaxf(mx, __shfl_xor(mx, off, 64));
      float sum = 0.f;
      #pragma unroll
      for (int tj = 0; tj < 4; ++tj) {
        const float p = __expf(acc[tj][r] - mx);
        acc[tj][r] = p;
        sum += p;
      }
      #pragma unroll
      for (int off = 1; off < 16; off <<= 1)
        sum += __shfl_xor(sum, off, 64);
      inv[r] = 1.0f / sum;  // normalization deferred to epilogue
    }

    // P tile (bf16) into Hs rows [16*ti, 16*ti+16) — tile-disjoint (no WAR across tiles)
    #pragma unroll
    for (int tj = 0; tj < 4; ++tj)
      #pragma unroll
      for (int r = 0; r < 4; ++r)
        Hs[(ti * 16 + g * 4 + r) * STR + tj * 16 + c16] = f2bf(acc[tj][r]);

    LDSWAIT();  // order ds_write(P) -> ds_read(pf) within the wave

    bf16x8 pf[2];
    #pragma unroll
    for (int kb = 0; kb < 2; ++kb)
      pf[kb] = *(const bf16x8*)&Hs[(ti * 16 + c16) * STR + kb * 32 + g * 8];

    f32x4 o[4];
    #pragma unroll
    for (int tjd = 0; tjd < 4; ++tjd) {
      f32x4 z = {0.f, 0.f, 0.f, 0.f};
      o[tjd] = z;
    }
    #pragma unroll
    for (int tjd = 0; tjd < 4; ++tjd)
      #pragma unroll
      for (int kb = 0; kb < 2; ++kb)
        o[tjd] = __builtin_amdgcn_mfma_f32_16x16x32_bf16(
            pf[kb], vf[tjd][kb], o[tjd], 0, 0, 0);

    #pragma unroll
    for (int r = 0; r < 4; ++r) {
      const int row = ti * 16 + g * 4 + r;
      if (row < L) {
        float* dst = out + (size_t)(start + row) * D;
        const float sc = inv[r];
        #pragma unroll
        for (int tjd = 0; tjd < 4; ++tjd)
          dst[tjd * 16 + c16] = o[tjd][r] * sc;
      }
    }
  }
}

extern "C" void kernel_launch(void* const* d_in, const int* in_sizes, int n_in,
                              void* d_out, int out_size, void* d_ws, size_t ws_size,
                              hipStream_t stream) {
  const float* h = (const float*)d_in[0];
  const int* sse = (const int*)d_in[1];
  float* out = (float*)d_out;
  const int nseq = in_sizes[1] / 2;  // 4096
  const int nblk = nseq / WAVES;     // 1024
  seq_attn_kernel<<<nblk, 64 * WAVES, 0, stream>>>(h, sse, out);
}